// Round 3
// baseline (516.681 us; speedup 1.0000x reference)
//
#include <hip/hip_runtime.h>
#include <math.h>

#define TOPK   4
#define NBINS  33          // MAX_NUM_BINS + 1
#define CPA    132         // corners per anchor = 4*33
#define STATD  20
#define HID    64
#define NCLS   80
#define APB    64          // anchors per block (output granularity)
#define CHA    32          // anchors per staged chunk
#define BS     256
#define HSTR   66          // s_h row stride: 64*66 floats == chunk buffer exactly
#define SBUF_F (CHA * CPA) // 4224 floats = 16896 B

// sort helper: compare-exchange, desc
#define CE(x, y) { const float _hi = fmaxf(x, y); const float _lo = fminf(x, y); x = _hi; y = _lo; }

// Fused: softmax+top4 -> stat -> MLP(20->64->1) -> scores + q, one block = 64 anchors
// LDS 22.3 KB -> 7 blocks/CU (28 waves, 87%) vs prior 39.4 KB (4 blocks, 50%)
__global__ __launch_bounds__(BS, 7) void lqe_fused(
    const float* __restrict__ scores,
    const float* __restrict__ corners,
    const float* __restrict__ W1,    // (20,64) row-major
    const float* __restrict__ b1,    // (64)
    const float* __restrict__ W2,    // (64,1)
    const float* __restrict__ b2,    // (1)
    float* __restrict__ out)
{
    __shared__ float s_buf[SBUF_F];           // 16896 B: corner chunk, then s_h overlay
    __shared__ float s_stat[APB * STATD];     //  5120 B
    __shared__ float s_q[APB];                //   256 B

    const int tid  = threadIdx.x;
    const int lane = tid & 63;
    const long long aBase = (long long)blockIdx.x * APB;

    // ==== phase 1a: two chunks of 32 anchors through one 16.9 KB buffer ====
    #pragma unroll
    for (int c = 0; c < 2; ++c) {
        // ---- stage chunk (coalesced float4): 1056 vec4 = 4 rounds + 32 tail ----
        {
            const float4* src = (const float4*)(corners + (aBase + c * CHA) * CPA);
            float4* dst = (float4*)s_buf;
            const float4 c0 = src[tid         ];
            const float4 c1 = src[tid + 1 * BS];
            const float4 c2 = src[tid + 2 * BS];
            const float4 c3 = src[tid + 3 * BS];
            float4 c4;
            const bool tl = tid < (SBUF_F / 4 - 4 * BS);   // 32 threads
            if (tl) c4 = src[tid + 4 * BS];
            dst[tid         ] = c0;
            dst[tid + 1 * BS] = c1;
            dst[tid + 2 * BS] = c2;
            dst[tid + 3 * BS] = c3;
            if (tl) dst[tid + 4 * BS] = c4;
        }
        __syncthreads();

        // ---- split-bin softmax+top4: 2 threads per (anchor,side), 17/16 bins ----
        {
            const int pid  = tid >> 1;          // 0..127 = (aLoc, side)
            const int h    = tid & 1;
            const int aL   = pid >> 2;          // 0..31
            const int side = pid & 3;
            // bank = (4*aL + side + 17*h + k) % 32 -> 2 lanes/bank: free
            const float* base = s_buf + aL * CPA + side * NBINS + h * 17;
            const int nb = 17 - h;              // h=0: bins 0..16, h=1: bins 17..32

            float p[17];
            #pragma unroll
            for (int k = 0; k < 17; ++k) p[k] = (k < nb) ? base[k] : -1e30f;

            float m = p[0];
            #pragma unroll
            for (int k = 1; k < 17; ++k) m = fmaxf(m, p[k]);
            m = fmaxf(m, __shfl_xor(m, 1, 64));             // pair max

            float s = 0.0f;
            #pragma unroll
            for (int k = 0; k < 17; ++k) { p[k] = __expf(p[k] - m); s += p[k]; }
            s += __shfl_xor(s, 1, 64);                      // pair sum (pad exp = 0)

            // per-thread top-4 over 17 exps (branchless insertion, desc)
            float t0 = -1.0f, t1 = -1.0f, t2 = -1.0f, t3 = -1.0f;
            #pragma unroll
            for (int k = 0; k < 17; ++k) {
                const float v  = p[k];
                const float b0 = fmaxf(t0, v),   d0 = fminf(t0, v);
                const float b1_ = fmaxf(t1, d0), d1 = fminf(t1, d0);
                const float b2_ = fmaxf(t2, d1), d2 = fminf(t2, d1);
                const float b3 = fmaxf(t3, d2);
                t0 = b0; t1 = b1_; t2 = b2_; t3 = b3;
            }

            // merge partner's sorted top-4: top4(A ∪ B)_i multiset = max(a_i, b_{3-i})
            const float u0 = __shfl_xor(t0, 1, 64);
            const float u1 = __shfl_xor(t1, 1, 64);
            const float u2 = __shfl_xor(t2, 1, 64);
            const float u3 = __shfl_xor(t3, 1, 64);
            float m0 = fmaxf(t0, u3), m1 = fmaxf(t1, u2);
            float m2 = fmaxf(t2, u1), m3 = fmaxf(t3, u0);
            // sort4 desc (5 CE)
            CE(m0, m1); CE(m2, m3); CE(m0, m2); CE(m1, m3); CE(m1, m2);

            const float inv = 1.0f / s;
            m0 *= inv; m1 *= inv; m2 *= inv; m3 *= inv;
            const float mean = (m0 + m1 + m2 + m3) * 0.25f;

            if (h == 0) {
                float* st = s_stat + (c * CHA + aL) * STATD + side * (TOPK + 1);
                st[0] = m0; st[1] = m1; st[2] = m2; st[3] = m3; st[4] = mean;
            }
        }
        __syncthreads();   // chunk0: before restage; chunk1: s_stat ready, s_buf dead
    }

    // ---- weights (small, L2-hot) ----
    float w1c[STATD];
    #pragma unroll
    for (int d = 0; d < STATD; ++d) w1c[d] = W1[d * HID + lane];
    const float bias = b1[lane];
    const float w2v  = W2[lane];
    const float b2v  = b2[0];

    // ---- phase 1b: MLP; wave handles 16 anchors, lane = hidden unit ----
    float* s_h = s_buf;   // [APB][HSTR] = 4224 floats, exact overlay
    {
        const int wave = tid >> 6;
        #pragma unroll
        for (int i = 0; i < APB / 4; ++i) {
            const int a = wave * (APB / 4) + i;
            const float4* sp = (const float4*)(s_stat + a * STATD);
            const float4 s0 = sp[0], s1 = sp[1], s2 = sp[2], s3 = sp[3], s4 = sp[4];
            float acc = bias;
            acc = fmaf(s0.x, w1c[0],  acc); acc = fmaf(s0.y, w1c[1],  acc);
            acc = fmaf(s0.z, w1c[2],  acc); acc = fmaf(s0.w, w1c[3],  acc);
            acc = fmaf(s1.x, w1c[4],  acc); acc = fmaf(s1.y, w1c[5],  acc);
            acc = fmaf(s1.z, w1c[6],  acc); acc = fmaf(s1.w, w1c[7],  acc);
            acc = fmaf(s2.x, w1c[8],  acc); acc = fmaf(s2.y, w1c[9],  acc);
            acc = fmaf(s2.z, w1c[10], acc); acc = fmaf(s2.w, w1c[11], acc);
            acc = fmaf(s3.x, w1c[12], acc); acc = fmaf(s3.y, w1c[13], acc);
            acc = fmaf(s3.z, w1c[14], acc); acc = fmaf(s3.w, w1c[15], acc);
            acc = fmaf(s4.x, w1c[16], acc); acc = fmaf(s4.y, w1c[17], acc);
            acc = fmaf(s4.z, w1c[18], acc); acc = fmaf(s4.w, w1c[19], acc);
            // bank = (2a + lane) % 32 -> 2 lanes/bank: free
            s_h[a * HSTR + lane] = fmaxf(acc, 0.0f) * w2v;
        }
    }
    __syncthreads();

    // ---- reduce: 4 threads/anchor, 16 values each via float2 (8B-aligned) ----
    {
        const int a  = tid >> 2;
        const int qd = tid & 3;
        const float2* hp = (const float2*)(s_h + a * HSTR + qd * 16);
        const float2 h0 = hp[0], h1 = hp[1], h2 = hp[2], h3 = hp[3];
        const float2 h4 = hp[4], h5 = hp[5], h6 = hp[6], h7 = hp[7];
        float v = (((h0.x + h0.y) + (h1.x + h1.y)) + ((h2.x + h2.y) + (h3.x + h3.y)))
                + (((h4.x + h4.y) + (h5.x + h5.y)) + ((h6.x + h6.y) + (h7.x + h7.y)));
        v += __shfl_xor(v, 1, 64);
        v += __shfl_xor(v, 2, 64);
        if (qd == 0) s_q[a] = v + b2v;
    }
    __syncthreads();

    // ---- streaming add + store (loads issue here; 28 resident waves hide them) ----
    {
        const float4* sc = (const float4*)(scores + aBase * NCLS);
        float4* op = (float4*)(out + aBase * NCLS);
        #pragma unroll
        for (int r = 0; r < 5; ++r) {
            const int j = tid + r * BS;
            const float qv = s_q[j / (NCLS / 4)];
            float4 v = sc[j];
            v.x += qv; v.y += qv; v.z += qv; v.w += qv;
            op[j] = v;
        }
    }
}

extern "C" void kernel_launch(void* const* d_in, const int* in_sizes, int n_in,
                              void* d_out, int out_size, void* d_ws, size_t ws_size,
                              hipStream_t stream) {
    const float* scores  = (const float*)d_in[0];
    const float* corners = (const float*)d_in[1];
    const float* W1      = (const float*)d_in[2];
    const float* b1      = (const float*)d_in[3];
    const float* W2      = (const float*)d_in[4];
    const float* b2      = (const float*)d_in[5];
    float* out = (float*)d_out;
    (void)d_ws; (void)ws_size;

    const int nAnchors = in_sizes[0] / NCLS;          // 524288
    const int blocks   = nAnchors / APB;              // 8192 (exact)

    lqe_fused<<<blocks, BS, 0, stream>>>(scores, corners, W1, b1, W2, b2, out);
}